// Round 6
// baseline (132.927 us; speedup 1.0000x reference)
//
#include <hip/hip_runtime.h>

#define NCH 128
#define NPA 2      // phase-A node partitions (50000 nodes -> 50KB u8 LDS hist)
#define GA  64     // phase-A edge groups
#define NPB 32     // phase-B node partitions (3125 nodes x f32x4 = 50KB LDS)
#define GB  16     // phase-B edge groups
#define BLK 256

// ---- Phase A: packed-u8 LDS histogram of in-degree, replica flush --------
// repA layout: [g][padded_node_word]  (NWtot u32 words per replica)
__global__ void k_histA(const int* __restrict__ col, int E, int PSA, int NWtot,
                        unsigned int* __restrict__ repA) {
    const int p = blockIdx.x / GA;
    const int g = blockIdx.x % GA;
    const int base = p * PSA;            // PSA multiple of 4
    const int nwords = PSA >> 2;
    __shared__ unsigned int hw[12544];   // >= 50000/4
    for (int j = threadIdx.x; j < nwords; j += BLK) hw[j] = 0u;
    __syncthreads();
    const int chunk = (E + GA - 1) / GA;
    const int e0 = g * chunk;
    const int e1 = min(e0 + chunk, E);
    for (int e = e0 + threadIdx.x; e < e1; e += BLK) {
        int c = col[e] - base;
        if ((unsigned)c < (unsigned)PSA)
            atomicAdd(&hw[c >> 2], 1u << ((c & 3) << 3));   // byte counter, max ~30
    }
    __syncthreads();
    unsigned int* dst = repA + (size_t)g * NWtot + (base >> 2);
    for (int j = threadIdx.x; j < nwords; j += BLK) dst[j] = hw[j];
}

// ---- reduce A + prep: deg -> dis, sx = dis * x ---------------------------
__global__ void k_reduceA(const unsigned int* __restrict__ repA,
                          const float4* __restrict__ x,
                          float4* __restrict__ sx, float* __restrict__ dis,
                          int n, int NWtot) {
    int t = blockIdx.x * blockDim.x + threadIdx.x;
    if (t >= NWtot) return;
    unsigned int w = 0;
    #pragma unroll
    for (int g = 0; g < GA; ++g) w += repA[(size_t)g * NWtot + t];
    #pragma unroll
    for (int b = 0; b < 4; ++b) {
        int node = (t << 2) + b;
        if (node < n) {
            float deg = (float)((w >> (b << 3)) & 255u);
            float di = rsqrtf(1.0f + deg);
            float4 v = x[node];
            sx[node] = make_float4(di * v.x, di * v.y, di * v.z, di * v.w);
            dis[node] = di;
        }
    }
}

// ---- Phase B: LDS f32x4 segment-sum of sx over edges, replica flush ------
// repB layout: [g][node*4 + ch]  (NT4 floats per replica)
__global__ void k_aggB(const int* __restrict__ row, const int* __restrict__ col,
                       const float4* __restrict__ sx, float* __restrict__ repB,
                       int E, int PSB, int NT4) {
    const int p = blockIdx.x / GB;
    const int g = blockIdx.x % GB;
    const int base = p * PSB;
    const int ps4 = PSB * 4;
    __shared__ float acc[12800];         // >= 3125*4 floats
    for (int j = threadIdx.x; j < ps4; j += BLK) acc[j] = 0.f;
    __syncthreads();
    const int chunk = (E + GB - 1) / GB;
    const int e0 = g * chunk;
    const int e1 = min(e0 + chunk, E);
    for (int e = e0 + threadIdx.x; e < e1; e += BLK) {
        int c = col[e] - base;
        if ((unsigned)c < (unsigned)PSB) {
            int r = row[e];
            float4 s = sx[r];
            atomicAdd(&acc[c * 4 + 0], s.x);
            atomicAdd(&acc[c * 4 + 1], s.y);
            atomicAdd(&acc[c * 4 + 2], s.z);
            atomicAdd(&acc[c * 4 + 3], s.w);
        }
    }
    __syncthreads();
    float* dst = repB + (size_t)g * NT4 + base * 4;
    for (int j = threadIdx.x; j < ps4; j += BLK) dst[j] = acc[j];
}

// ---- reduce B: m = dis * (sum_g rep + sx_self) ---------------------------
__global__ void k_reduceB(const float* __restrict__ repB,
                          const float4* __restrict__ sx, const float* __restrict__ dis,
                          float4* __restrict__ m, int n, int NT4) {
    int i = blockIdx.x * blockDim.x + threadIdx.x;
    if (i >= n) return;
    float4 a = sx[i];                    // self term (dis_i * x_i)
    float ax = a.x, ay = a.y, az = a.z, aw = a.w;
    #pragma unroll
    for (int g = 0; g < GB; ++g) {
        const float4* rp = (const float4*)(repB + (size_t)g * NT4);
        float4 v = rp[i];
        ax += v.x; ay += v.y; az += v.z; aw += v.w;
    }
    float di = dis[i];
    m[i] = make_float4(di * ax, di * ay, di * az, di * aw);
}

// ---- out[i][c] = m_i . W[:,c] + b[c] -------------------------------------
__global__ void k_out(const float4* __restrict__ m, const float* __restrict__ W,
                      const float* __restrict__ b, float* __restrict__ out, int n) {
    int t = blockIdx.x * blockDim.x + threadIdx.x;   // node*32 + c4grp
    if (t >= n * 32) return;
    int i  = t >> 5;
    int c4 = (t & 31) * 4;

    float4 mi = m[i];
    float4 w0 = *(const float4*)&W[0 * NCH + c4];
    float4 w1 = *(const float4*)&W[1 * NCH + c4];
    float4 w2 = *(const float4*)&W[2 * NCH + c4];
    float4 w3 = *(const float4*)&W[3 * NCH + c4];
    float4 bb = *(const float4*)&b[c4];

    float4 o;
    o.x = mi.x * w0.x + mi.y * w1.x + mi.z * w2.x + mi.w * w3.x + bb.x;
    o.y = mi.x * w0.y + mi.y * w1.y + mi.z * w2.y + mi.w * w3.y + bb.y;
    o.z = mi.x * w0.z + mi.y * w1.z + mi.z * w2.z + mi.w * w3.z + bb.z;
    o.w = mi.x * w0.w + mi.y * w1.w + mi.z * w2.w + mi.w * w3.w + bb.w;
    ((float4*)out)[t] = o;
}

extern "C" void kernel_launch(void* const* d_in, const int* in_sizes, int n_in,
                              void* d_out, int out_size, void* d_ws, size_t ws_size,
                              hipStream_t stream) {
    const float* x  = (const float*)d_in[0];
    const int*   ei = (const int*)d_in[1];     // int64 in ref -> pushed as int32
    const float* W  = (const float*)d_in[2];
    const float* b  = (const float*)d_in[3];
    float* out = (float*)d_out;

    int n = in_sizes[0] / 4;       // 100000
    int E = in_sizes[1] / 2;       // 640000
    const int* row = ei;           // sources
    const int* col = ei + E;       // targets

    // phase-A partition size: ceil(n/NPA) rounded up to multiple of 4
    int PSA = ((n + NPA * 4 - 1) / (NPA * 4)) * 4;      // 50000
    int NWtot = (NPA * PSA) >> 2;                       // 25000 words / replica
    // phase-B partition size
    int PSB = (n + NPB - 1) / NPB;                      // 3125
    int NT4 = NPB * PSB * 4;                            // 400000 floats / replica

    // ws layout (4B units):
    //   sx[4n] | mbuf[4n] | dis[n] | repA[GA*NWtot] | repB[GB*NT4]
    float*        sx   = (float*)d_ws;
    float*        mbuf = (float*)d_ws + 4 * (size_t)n;
    float*        dis  = (float*)d_ws + 8 * (size_t)n;
    unsigned int* repA = (unsigned int*)d_ws + 9 * (size_t)n;
    float*        repB = (float*)d_ws + 9 * (size_t)n + (size_t)GA * NWtot;

    k_histA  <<<NPA * GA, BLK, 0, stream>>>(col, E, PSA, NWtot, repA);
    k_reduceA<<<(NWtot + BLK - 1) / BLK, BLK, 0, stream>>>(repA, (const float4*)x,
                                                           (float4*)sx, dis, n, NWtot);
    k_aggB   <<<NPB * GB, BLK, 0, stream>>>(row, col, (const float4*)sx, repB,
                                            E, PSB, NT4);
    k_reduceB<<<(n + BLK - 1) / BLK, BLK, 0, stream>>>(repB, (const float4*)sx, dis,
                                                       (float4*)mbuf, n, NT4);
    int oT = n * 32;
    k_out    <<<(oT + BLK - 1) / BLK, BLK, 0, stream>>>((const float4*)mbuf, W, b, out, n);
}

// Round 7
// 109.026 us; speedup vs baseline: 1.2192x; 1.2192x over previous
//
#include <hip/hip_runtime.h>

#define NCH 128
#define BLK 256

// Phase A (degree histogram): NPA node partitions x GA edge groups
#define NPA 4
#define PSA 25000      // nodes per partition (multiple of 4)
#define NWA 6250       // u32 words per partition (4 packed u8 per word)
#define NWTOT 25000    // words per replica (= NPA*NWA)
#define GA  128

// Phase B (f32x4 segment sum): NPB node partitions x GB edge groups
#define NPB 64
#define PSB 1563       // ceil(100000/64)
#define GB  16
#define REP4 (NPB*PSB) // float4 slots per replica (100032)

// ---- A: packed-u8 LDS in-degree histogram, replica flush -----------------
__global__ void k_histA(const int* __restrict__ col, int E,
                        unsigned int* __restrict__ repA) {
    const int p = blockIdx.x / GA;
    const int g = blockIdx.x % GA;
    const int base = p * PSA;
    __shared__ unsigned int hw[NWA];
    for (int j = threadIdx.x; j < NWA; j += BLK) hw[j] = 0u;
    __syncthreads();
    const int chunk = (E + GA - 1) / GA;
    const int e0 = g * chunk;
    const int e1 = min(e0 + chunk, E);
    #pragma unroll 4
    for (int e = e0 + threadIdx.x; e < e1; e += BLK) {
        unsigned int c = (unsigned int)(col[e] - base);
        if (c < (unsigned)PSA)
            atomicAdd(&hw[c >> 2], 1u << ((c & 3u) << 3));  // u8 counters, deg<=~30
    }
    __syncthreads();
    unsigned int* dst = repA + (size_t)g * NWTOT + (base >> 2);
    for (int j = threadIdx.x; j < NWA; j += BLK) dst[j] = hw[j];
}

// ---- A-reduce: deg -> dis, sx = dis * x ----------------------------------
__global__ void k_reduceA(const unsigned int* __restrict__ repA,
                          const float4* __restrict__ x,
                          float4* __restrict__ sx, float* __restrict__ dis, int n) {
    int t = blockIdx.x * blockDim.x + threadIdx.x;
    if (t >= NWTOT) return;
    unsigned int w = 0;
    #pragma unroll
    for (int g = 0; g < GA; ++g) w += repA[(size_t)g * NWTOT + t];
    #pragma unroll
    for (int bb = 0; bb < 4; ++bb) {
        int node = (t << 2) + bb;
        if (node < n) {
            float deg = (float)((w >> (bb << 3)) & 255u);
            float di = rsqrtf(1.0f + deg);
            float4 v = x[node];
            sx[node] = make_float4(di * v.x, di * v.y, di * v.z, di * v.w);
            dis[node] = di;
        }
    }
}

// ---- msg expansion: msg[e] = sx[row[e]]  (high-occupancy random gather) --
__global__ void k_msg(const int* __restrict__ row, const float4* __restrict__ sx,
                      float4* __restrict__ msg, int E) {
    int e = blockIdx.x * blockDim.x + threadIdx.x;
    if (e < E) msg[e] = sx[row[e]];
}

// ---- B: LDS f32x4 segment sum over streamed (col, msg), replica flush ----
__global__ void k_aggB(const int* __restrict__ col, const float4* __restrict__ msg,
                       float4* __restrict__ repB, int E) {
    const int p = blockIdx.x / GB;
    const int g = blockIdx.x % GB;
    const int base = p * PSB;
    __shared__ float acc[PSB * 4];
    for (int j = threadIdx.x; j < PSB * 4; j += BLK) acc[j] = 0.f;
    __syncthreads();
    const int chunk = (E + GB - 1) / GB;
    const int e0 = g * chunk;
    const int e1 = min(e0 + chunk, E);
    #pragma unroll 4
    for (int e = e0 + threadIdx.x; e < e1; e += BLK) {
        unsigned int lc = (unsigned int)(col[e] - base);
        if (lc < (unsigned)PSB) {
            float4 v = msg[e];                 // sparse (1/NPB), independent load
            atomicAdd(&acc[lc * 4 + 0], v.x);
            atomicAdd(&acc[lc * 4 + 1], v.y);
            atomicAdd(&acc[lc * 4 + 2], v.z);
            atomicAdd(&acc[lc * 4 + 3], v.w);
        }
    }
    __syncthreads();
    float4* dst = repB + (size_t)g * REP4 + base;
    const float4* a4 = (const float4*)acc;
    for (int j = threadIdx.x; j < PSB; j += BLK) dst[j] = a4[j];
}

// ---- B-reduce: m = dis * (sum_g rep + sx_self) ---------------------------
__global__ void k_reduceB(const float4* __restrict__ repB,
                          const float4* __restrict__ sx, const float* __restrict__ dis,
                          float4* __restrict__ m, int n) {
    int i = blockIdx.x * blockDim.x + threadIdx.x;
    if (i >= n) return;
    float4 a = sx[i];                          // self term (dis_i * x_i)
    float ax = a.x, ay = a.y, az = a.z, aw = a.w;
    #pragma unroll
    for (int g = 0; g < GB; ++g) {
        float4 v = repB[(size_t)g * REP4 + i];
        ax += v.x; ay += v.y; az += v.z; aw += v.w;
    }
    float di = dis[i];
    m[i] = make_float4(di * ax, di * ay, di * az, di * aw);
}

// ---- out[i][c] = m_i . W[:,c] + b[c] -------------------------------------
__global__ void k_out(const float4* __restrict__ m, const float* __restrict__ W,
                      const float* __restrict__ b, float* __restrict__ out, int n) {
    int t = blockIdx.x * blockDim.x + threadIdx.x;   // node*32 + c4grp
    if (t >= n * 32) return;
    int i  = t >> 5;
    int c4 = (t & 31) * 4;

    float4 mi = m[i];
    float4 w0 = *(const float4*)&W[0 * NCH + c4];
    float4 w1 = *(const float4*)&W[1 * NCH + c4];
    float4 w2 = *(const float4*)&W[2 * NCH + c4];
    float4 w3 = *(const float4*)&W[3 * NCH + c4];
    float4 bb = *(const float4*)&b[c4];

    float4 o;
    o.x = mi.x * w0.x + mi.y * w1.x + mi.z * w2.x + mi.w * w3.x + bb.x;
    o.y = mi.x * w0.y + mi.y * w1.y + mi.z * w2.y + mi.w * w3.y + bb.y;
    o.z = mi.x * w0.z + mi.y * w1.z + mi.z * w2.z + mi.w * w3.z + bb.z;
    o.w = mi.x * w0.w + mi.y * w1.w + mi.z * w2.w + mi.w * w3.w + bb.w;
    ((float4*)out)[t] = o;
}

extern "C" void kernel_launch(void* const* d_in, const int* in_sizes, int n_in,
                              void* d_out, int out_size, void* d_ws, size_t ws_size,
                              hipStream_t stream) {
    const float* x  = (const float*)d_in[0];
    const int*   ei = (const int*)d_in[1];     // int64 in ref -> pushed as int32
    const float* W  = (const float*)d_in[2];
    const float* b  = (const float*)d_in[3];
    float* out = (float*)d_out;

    int n = in_sizes[0] / 4;       // 100000
    int E = in_sizes[1] / 2;       // 640000
    const int* row = ei;           // sources
    const int* col = ei + E;       // targets

    // ws layout (4B units):
    //  sx[4n] | dis[n] | m[4n] | msg[4E] | repA[GA*NWTOT] | repB[GB*REP4*4]
    float*        sx   = (float*)d_ws;
    float*        dis  = (float*)d_ws + 4 * (size_t)n;
    float*        mbuf = (float*)d_ws + 5 * (size_t)n;
    float*        msg  = (float*)d_ws + 9 * (size_t)n;
    unsigned int* repA = (unsigned int*)d_ws + 9 * (size_t)n + 4 * (size_t)E;
    float*        repB = (float*)d_ws + 9 * (size_t)n + 4 * (size_t)E
                         + (size_t)GA * NWTOT;

    k_histA  <<<NPA * GA, BLK, 0, stream>>>(col, E, repA);
    k_reduceA<<<(NWTOT + BLK - 1) / BLK, BLK, 0, stream>>>(repA, (const float4*)x,
                                                           (float4*)sx, dis, n);
    k_msg    <<<(E + BLK - 1) / BLK, BLK, 0, stream>>>(row, (const float4*)sx,
                                                       (float4*)msg, E);
    k_aggB   <<<NPB * GB, BLK, 0, stream>>>(col, (const float4*)msg,
                                            (float4*)repB, E);
    k_reduceB<<<(n + BLK - 1) / BLK, BLK, 0, stream>>>((const float4*)repB,
                                                       (const float4*)sx, dis,
                                                       (float4*)mbuf, n);
    int oT = n * 32;
    k_out    <<<(oT + BLK - 1) / BLK, BLK, 0, stream>>>((const float4*)mbuf, W, b, out, n);
}

// Round 8
// 84.928 us; speedup vs baseline: 1.5652x; 1.2837x over previous
//
#include <hip/hip_runtime.h>

#define NCH 128
#define BLK 256

// Phase A (degree histogram): NPA node partitions x GA edge groups
#define NPA 4
#define PSA 25000      // nodes per partition (multiple of 4)
#define NWA 6250       // u32 words per partition (4 packed u8 per word)
#define NWTOT 25000    // words per replica
#define GA  128

// Bucketing: pow2 partitions
#define PSB 2048
#define LGP 11
#define NBKM 64        // max buckets (actual nbk = 49)
#define NB  256        // bucket-count / fill blocks
#define GB2 8          // aggregation sub-blocks per bucket

// ---- A: packed-u8 LDS in-degree histogram, replica flush -----------------
__global__ void k_histA(const int* __restrict__ col, int E,
                        unsigned int* __restrict__ repA) {
    const int p = blockIdx.x / GA;
    const int g = blockIdx.x % GA;
    const int base = p * PSA;
    __shared__ unsigned int hw[NWA];
    for (int j = threadIdx.x; j < NWA; j += BLK) hw[j] = 0u;
    __syncthreads();
    const int chunk = (E + GA - 1) / GA;
    const int e0 = g * chunk;
    const int e1 = min(e0 + chunk, E);
    for (int e = e0 + threadIdx.x; e < e1; e += BLK) {
        unsigned int c = (unsigned int)(col[e] - base);
        if (c < (unsigned)PSA)
            atomicAdd(&hw[c >> 2], 1u << ((c & 3u) << 3));  // u8 counters, deg<=~30
    }
    __syncthreads();
    unsigned int* dst = repA + (size_t)g * NWTOT + (base >> 2);
    for (int j = threadIdx.x; j < NWA; j += BLK) dst[j] = hw[j];
}

// ---- A-reduce: deg -> dis, sx = dis * x ----------------------------------
__global__ void k_reduceA(const unsigned int* __restrict__ repA,
                          const float4* __restrict__ x,
                          float4* __restrict__ sx, float* __restrict__ dis, int n) {
    int t = blockIdx.x * blockDim.x + threadIdx.x;
    if (t >= NWTOT) return;
    unsigned int w = 0;
    #pragma unroll
    for (int g = 0; g < GA; ++g) w += repA[(size_t)g * NWTOT + t];
    #pragma unroll
    for (int bb = 0; bb < 4; ++bb) {
        int node = (t << 2) + bb;
        if (node < n) {
            float deg = (float)((w >> (bb << 3)) & 255u);
            float di = rsqrtf(1.0f + deg);
            float4 v = x[node];
            sx[node] = make_float4(di * v.x, di * v.y, di * v.z, di * v.w);
            dis[node] = di;
        }
    }
}

// ---- bucket counts: bcntT[bucket][blk] -----------------------------------
__global__ void k_bcnt(const int* __restrict__ col, int E,
                       unsigned int* __restrict__ bcntT) {
    __shared__ unsigned int bc[NBKM];
    const int g = blockIdx.x;
    if (threadIdx.x < NBKM) bc[threadIdx.x] = 0u;
    __syncthreads();
    const int chunk = (E + NB - 1) / NB;
    const int e0 = g * chunk;
    const int e1 = min(e0 + chunk, E);
    for (int e = e0 + threadIdx.x; e < e1; e += BLK)
        atomicAdd(&bc[((unsigned)col[e]) >> LGP], 1u);
    __syncthreads();
    if (threadIdx.x < NBKM) bcntT[threadIdx.x * NB + g] = bc[threadIdx.x];
}

// ---- scan1: per bucket, exclusive scan over NB block-counts --------------
__global__ void k_scan1(const unsigned int* __restrict__ bcntT,
                        unsigned int* __restrict__ cpart,
                        unsigned int* __restrict__ btot) {
    __shared__ unsigned int s[NB];
    const int p = blockIdx.x;       // 0..63
    const int t = threadIdx.x;      // 0..255
    unsigned int v = bcntT[p * NB + t];
    s[t] = v;
    __syncthreads();
    for (int off = 1; off < NB; off <<= 1) {
        unsigned int u = (t >= off) ? s[t - off] : 0u;
        __syncthreads();
        s[t] += u;
        __syncthreads();
    }
    cpart[p * NB + t] = s[t] - v;
    if (t == NB - 1) btot[p] = s[t];
}

// ---- scan2: exclusive scan of 64 bucket totals ---------------------------
__global__ void k_scan2(const unsigned int* __restrict__ btot,
                        unsigned int* __restrict__ boffs) {
    __shared__ unsigned int s[NBKM];
    const int t = threadIdx.x;      // 0..63
    unsigned int v = btot[t];
    s[t] = v;
    __syncthreads();
    for (int off = 1; off < NBKM; off <<= 1) {
        unsigned int u = (t >= off) ? s[t - off] : 0u;
        __syncthreads();
        s[t] += u;
        __syncthreads();
    }
    boffs[t] = s[t] - v;
}

// ---- fill: route each edge's (lc, msg) into its bucket segment -----------
__global__ void k_bfill(const int* __restrict__ row, const int* __restrict__ col,
                        const float4* __restrict__ sx,
                        const unsigned int* __restrict__ cpart,
                        const unsigned int* __restrict__ boffs,
                        float4* __restrict__ bmsg, int* __restrict__ blc, int E) {
    __shared__ unsigned int cur[NBKM];
    const int g = blockIdx.x;
    if (threadIdx.x < NBKM)
        cur[threadIdx.x] = boffs[threadIdx.x] + cpart[threadIdx.x * NB + g];
    __syncthreads();
    const int chunk = (E + NB - 1) / NB;
    const int e0 = g * chunk;
    const int e1 = min(e0 + chunk, E);
    for (int e = e0 + threadIdx.x; e < e1; e += BLK) {
        int cv = col[e];
        unsigned int slot = atomicAdd(&cur[((unsigned)cv) >> LGP], 1u);
        bmsg[slot] = sx[row[e]];
        blc[slot]  = cv & (PSB - 1);
    }
}

// ---- aggregate: one bucket sub-range per block, linear stream ------------
__global__ void k_baggB(const int* __restrict__ blc, const float4* __restrict__ bmsg,
                        const unsigned int* __restrict__ boffs,
                        const unsigned int* __restrict__ btot,
                        float4* __restrict__ repB, int rstride) {
    const int p = blockIdx.x / GB2;
    const int g = blockIdx.x % GB2;
    __shared__ float acc[PSB * 4];              // 32 KB
    float4* a4 = (float4*)acc;
    for (int j = threadIdx.x; j < PSB; j += BLK) a4[j] = make_float4(0.f,0.f,0.f,0.f);
    __syncthreads();
    unsigned int s = boffs[p], len = btot[p];
    unsigned int ch = (len + GB2 - 1) / GB2;
    unsigned int e0 = s + g * ch;
    unsigned int e1 = min(e0 + ch, s + len);
    for (unsigned int e = e0 + threadIdx.x; e < e1; e += BLK) {
        int lc = blc[e];
        float4 v = bmsg[e];
        atomicAdd(&acc[lc * 4 + 0], v.x);
        atomicAdd(&acc[lc * 4 + 1], v.y);
        atomicAdd(&acc[lc * 4 + 2], v.z);
        atomicAdd(&acc[lc * 4 + 3], v.w);
    }
    __syncthreads();
    float4* dst = repB + (size_t)g * rstride + p * PSB;
    for (int j = threadIdx.x; j < PSB; j += BLK) dst[j] = a4[j];
}

// ---- B-reduce: m = dis * (sum_g rep + sx_self) ---------------------------
__global__ void k_reduceB(const float4* __restrict__ repB,
                          const float4* __restrict__ sx, const float* __restrict__ dis,
                          float4* __restrict__ m, int n, int rstride) {
    int i = blockIdx.x * blockDim.x + threadIdx.x;
    if (i >= n) return;
    float4 a = sx[i];                           // self term (dis_i * x_i)
    float ax = a.x, ay = a.y, az = a.z, aw = a.w;
    #pragma unroll
    for (int g = 0; g < GB2; ++g) {
        float4 v = repB[(size_t)g * rstride + i];
        ax += v.x; ay += v.y; az += v.z; aw += v.w;
    }
    float di = dis[i];
    m[i] = make_float4(di * ax, di * ay, di * az, di * aw);
}

// ---- out[i][c] = m_i . W[:,c] + b[c] -------------------------------------
__global__ void k_out(const float4* __restrict__ m, const float* __restrict__ W,
                      const float* __restrict__ b, float* __restrict__ out, int n) {
    int t = blockIdx.x * blockDim.x + threadIdx.x;   // node*32 + c4grp
    if (t >= n * 32) return;
    int i  = t >> 5;
    int c4 = (t & 31) * 4;

    float4 mi = m[i];
    float4 w0 = *(const float4*)&W[0 * NCH + c4];
    float4 w1 = *(const float4*)&W[1 * NCH + c4];
    float4 w2 = *(const float4*)&W[2 * NCH + c4];
    float4 w3 = *(const float4*)&W[3 * NCH + c4];
    float4 bb = *(const float4*)&b[c4];

    float4 o;
    o.x = mi.x * w0.x + mi.y * w1.x + mi.z * w2.x + mi.w * w3.x + bb.x;
    o.y = mi.x * w0.y + mi.y * w1.y + mi.z * w2.y + mi.w * w3.y + bb.y;
    o.z = mi.x * w0.z + mi.y * w1.z + mi.z * w2.z + mi.w * w3.z + bb.z;
    o.w = mi.x * w0.w + mi.y * w1.w + mi.z * w2.w + mi.w * w3.w + bb.w;
    ((float4*)out)[t] = o;
}

extern "C" void kernel_launch(void* const* d_in, const int* in_sizes, int n_in,
                              void* d_out, int out_size, void* d_ws, size_t ws_size,
                              hipStream_t stream) {
    const float* x  = (const float*)d_in[0];
    const int*   ei = (const int*)d_in[1];     // int64 in ref -> pushed as int32
    const float* W  = (const float*)d_in[2];
    const float* b  = (const float*)d_in[3];
    float* out = (float*)d_out;

    int n = in_sizes[0] / 4;       // 100000
    int E = in_sizes[1] / 2;       // 640000
    const int* row = ei;           // sources
    const int* col = ei + E;       // targets

    int nbk = (n + PSB - 1) >> LGP;            // 49 buckets
    int rstride = nbk * PSB;                   // float4 per replica (100352)

    // ws layout (4B units, all float4 offsets multiple of 4):
    //  sx[4n] | dis[n] | m[4n] | bmsg[4E] | blc[E] | repA[GA*NWTOT]
    //  | bcntT[64*NB] | cpart[64*NB] | btot[64] | boffs[64] | repB[GB2*rstride*4]
    size_t o_sx    = 0;
    size_t o_dis   = o_sx + 4 * (size_t)n;
    size_t o_m     = o_dis + (size_t)n;
    size_t o_bmsg  = o_m + 4 * (size_t)n;
    size_t o_blc   = o_bmsg + 4 * (size_t)E;
    size_t o_repA  = o_blc + (size_t)E;
    size_t o_bcnt  = o_repA + (size_t)GA * NWTOT;
    size_t o_cpart = o_bcnt + (size_t)NBKM * NB;
    size_t o_btot  = o_cpart + (size_t)NBKM * NB;
    size_t o_boffs = o_btot + NBKM;
    size_t o_repB  = (o_boffs + NBKM + 3) & ~(size_t)3;   // 16B align

    float*        sx    = (float*)d_ws + o_sx;
    float*        dis   = (float*)d_ws + o_dis;
    float*        mbuf  = (float*)d_ws + o_m;
    float4*       bmsg  = (float4*)((float*)d_ws + o_bmsg);
    int*          blc   = (int*)d_ws + o_blc;
    unsigned int* repA  = (unsigned int*)d_ws + o_repA;
    unsigned int* bcntT = (unsigned int*)d_ws + o_bcnt;
    unsigned int* cpart = (unsigned int*)d_ws + o_cpart;
    unsigned int* btot  = (unsigned int*)d_ws + o_btot;
    unsigned int* boffs = (unsigned int*)d_ws + o_boffs;
    float4*       repB  = (float4*)((float*)d_ws + o_repB);

    k_histA  <<<NPA * GA, BLK, 0, stream>>>(col, E, repA);
    k_bcnt   <<<NB, BLK, 0, stream>>>(col, E, bcntT);
    k_reduceA<<<(NWTOT + BLK - 1) / BLK, BLK, 0, stream>>>(repA, (const float4*)x,
                                                           (float4*)sx, dis, n);
    k_scan1  <<<NBKM, NB, 0, stream>>>(bcntT, cpart, btot);
    k_scan2  <<<1, NBKM, 0, stream>>>(btot, boffs);
    k_bfill  <<<NB, BLK, 0, stream>>>(row, col, (const float4*)sx, cpart, boffs,
                                      bmsg, blc, E);
    k_baggB  <<<nbk * GB2, BLK, 0, stream>>>(blc, bmsg, boffs, btot, repB, rstride);
    k_reduceB<<<(n + BLK - 1) / BLK, BLK, 0, stream>>>(repB, (const float4*)sx, dis,
                                                       (float4*)mbuf, n, rstride);
    int oT = n * 32;
    k_out    <<<(oT + BLK - 1) / BLK, BLK, 0, stream>>>((const float4*)mbuf, W, b, out, n);
}

// Round 9
// 70.205 us; speedup vs baseline: 1.8934x; 1.2097x over previous
//
#include <hip/hip_runtime.h>

#define NCH 128
#define BLK 256

// Bucketing: pow2 node partitions
#define PSB  1024
#define LGP  10
#define NBKM 128          // padded bucket count (actual nbk = 98)
#define NB   256          // count/fill edge-stream blocks
#define GB2  4            // sub-blocks per bucket (deg + agg)
#define NSTR (NBKM * PSB) // per-replica node stride (131072)

// ---- 1. bucket counts: bcntT[bucket][blk] --------------------------------
__global__ void k_bcnt(const int* __restrict__ col, int E, int nbk,
                       unsigned int* __restrict__ bcntT) {
    __shared__ unsigned int bc[NBKM];
    const int g = blockIdx.x;
    for (int j = threadIdx.x; j < nbk; j += BLK) bc[j] = 0u;
    __syncthreads();
    const int chunk = (E + NB - 1) / NB;
    const int e0 = g * chunk;
    const int e1 = min(e0 + chunk, E);
    for (int e = e0 + threadIdx.x; e < e1; e += BLK)
        atomicAdd(&bc[((unsigned)col[e]) >> LGP], 1u);
    __syncthreads();
    for (int j = threadIdx.x; j < nbk; j += BLK) bcntT[j * NB + g] = bc[j];
}

// ---- 2. per-bucket exclusive scan over NB block counts -------------------
__global__ void k_scan1(const unsigned int* __restrict__ bcntT,
                        unsigned int* __restrict__ cpart,
                        unsigned int* __restrict__ btot) {
    __shared__ unsigned int s[NB];
    const int p = blockIdx.x;
    const int t = threadIdx.x;
    unsigned int v = bcntT[p * NB + t];
    s[t] = v;
    __syncthreads();
    for (int off = 1; off < NB; off <<= 1) {
        unsigned int u = (t >= off) ? s[t - off] : 0u;
        __syncthreads();
        s[t] += u;
        __syncthreads();
    }
    cpart[p * NB + t] = s[t] - v;
    if (t == NB - 1) btot[p] = s[t];
}

// ---- 3. exclusive scan of bucket totals ----------------------------------
__global__ void k_scan2(const unsigned int* __restrict__ btot,
                        unsigned int* __restrict__ boffs, int nbk) {
    __shared__ unsigned int s[NBKM];
    const int t = threadIdx.x;
    unsigned int v = (t < nbk) ? btot[t] : 0u;
    s[t] = v;
    __syncthreads();
    for (int off = 1; off < NBKM; off <<= 1) {
        unsigned int u = (t >= off) ? s[t - off] : 0u;
        __syncthreads();
        s[t] += u;
        __syncthreads();
    }
    if (t < nbk) boffs[t] = s[t] - v;
}

// ---- 4. fill: route (lc:u16, row:int) into bucket segments ---------------
__global__ void k_bfill(const int* __restrict__ row, const int* __restrict__ col,
                        const unsigned int* __restrict__ cpart,
                        const unsigned int* __restrict__ boffs,
                        unsigned short* __restrict__ blc, int* __restrict__ brow,
                        int E, int nbk) {
    __shared__ unsigned int cur[NBKM];
    const int g = blockIdx.x;
    for (int j = threadIdx.x; j < nbk; j += BLK)
        cur[j] = boffs[j] + cpart[j * NB + g];
    __syncthreads();
    const int chunk = (E + NB - 1) / NB;
    const int e0 = g * chunk;
    const int e1 = min(e0 + chunk, E);
    for (int e = e0 + threadIdx.x; e < e1; e += BLK) {
        int cv = col[e];
        unsigned int slot = atomicAdd(&cur[((unsigned)cv) >> LGP], 1u);
        blc[slot]  = (unsigned short)(cv & (PSB - 1));
        brow[slot] = row[e];
    }
}

// ---- 5. per-bucket degree count (4 KB LDS), replica flush ----------------
__global__ void k_bdeg(const unsigned short* __restrict__ blc,
                       const unsigned int* __restrict__ boffs,
                       const unsigned int* __restrict__ btot,
                       unsigned int* __restrict__ degrep) {
    const int p = blockIdx.x / GB2;
    const int g = blockIdx.x % GB2;
    __shared__ unsigned int dcnt[PSB];
    for (int j = threadIdx.x; j < PSB; j += BLK) dcnt[j] = 0u;
    __syncthreads();
    unsigned int s = boffs[p], len = btot[p];
    unsigned int ch = (len + GB2 - 1) / GB2;
    unsigned int e0 = s + g * ch;
    unsigned int e1 = min(e0 + ch, s + len);
    for (unsigned int e = e0 + threadIdx.x; e < e1; e += BLK)
        atomicAdd(&dcnt[blc[e]], 1u);
    __syncthreads();
    unsigned int* dst = degrep + (size_t)g * NSTR + p * PSB;
    for (int j = threadIdx.x; j < PSB; j += BLK) dst[j] = dcnt[j];
}

// ---- 6. dis = rsqrt(1+deg), sx = dis * x ---------------------------------
__global__ void k_dsx(const unsigned int* __restrict__ degrep,
                      const float4* __restrict__ x,
                      float4* __restrict__ sx, float* __restrict__ dis, int n) {
    int i = blockIdx.x * blockDim.x + threadIdx.x;
    if (i >= n) return;
    unsigned int d = 0;
    #pragma unroll
    for (int g = 0; g < GB2; ++g) d += degrep[(size_t)g * NSTR + i];
    float di = rsqrtf(1.0f + (float)d);
    float4 v = x[i];
    sx[i] = make_float4(di * v.x, di * v.y, di * v.z, di * v.w);
    dis[i] = di;
}

// ---- 7. bucket aggregation: stream (blc, brow), gather sx, 16 KB LDS -----
__global__ void k_baggB(const unsigned short* __restrict__ blc,
                        const int* __restrict__ brow,
                        const float4* __restrict__ sx,
                        const unsigned int* __restrict__ boffs,
                        const unsigned int* __restrict__ btot,
                        float4* __restrict__ repB) {
    const int p = blockIdx.x / GB2;
    const int g = blockIdx.x % GB2;
    __shared__ float acc[PSB * 4];              // 16 KB
    float4* a4 = (float4*)acc;
    for (int j = threadIdx.x; j < PSB; j += BLK) a4[j] = make_float4(0.f,0.f,0.f,0.f);
    __syncthreads();
    unsigned int s = boffs[p], len = btot[p];
    unsigned int ch = (len + GB2 - 1) / GB2;
    unsigned int e0 = s + g * ch;
    unsigned int e1 = min(e0 + ch, s + len);
    for (unsigned int e = e0 + threadIdx.x; e < e1; e += BLK) {
        int lc = blc[e];
        float4 v = sx[brow[e]];                 // L2-resident random gather
        atomicAdd(&acc[lc * 4 + 0], v.x);
        atomicAdd(&acc[lc * 4 + 1], v.y);
        atomicAdd(&acc[lc * 4 + 2], v.z);
        atomicAdd(&acc[lc * 4 + 3], v.w);
    }
    __syncthreads();
    float4* dst = repB + (size_t)g * NSTR + p * PSB;
    for (int j = threadIdx.x; j < PSB; j += BLK) dst[j] = a4[j];
}

// ---- 8. m = dis * (sum_g rep + sx_self) ----------------------------------
__global__ void k_reduceB(const float4* __restrict__ repB,
                          const float4* __restrict__ sx, const float* __restrict__ dis,
                          float4* __restrict__ m, int n) {
    int i = blockIdx.x * blockDim.x + threadIdx.x;
    if (i >= n) return;
    float4 a = sx[i];
    float ax = a.x, ay = a.y, az = a.z, aw = a.w;
    #pragma unroll
    for (int g = 0; g < GB2; ++g) {
        float4 v = repB[(size_t)g * NSTR + i];
        ax += v.x; ay += v.y; az += v.z; aw += v.w;
    }
    float di = dis[i];
    m[i] = make_float4(di * ax, di * ay, di * az, di * aw);
}

// ---- 9. out[i][c] = m_i . W[:,c] + b[c] ----------------------------------
__global__ void k_out(const float4* __restrict__ m, const float* __restrict__ W,
                      const float* __restrict__ b, float* __restrict__ out, int n) {
    int t = blockIdx.x * blockDim.x + threadIdx.x;   // node*32 + c4grp
    if (t >= n * 32) return;
    int i  = t >> 5;
    int c4 = (t & 31) * 4;

    float4 mi = m[i];
    float4 w0 = *(const float4*)&W[0 * NCH + c4];
    float4 w1 = *(const float4*)&W[1 * NCH + c4];
    float4 w2 = *(const float4*)&W[2 * NCH + c4];
    float4 w3 = *(const float4*)&W[3 * NCH + c4];
    float4 bb = *(const float4*)&b[c4];

    float4 o;
    o.x = mi.x * w0.x + mi.y * w1.x + mi.z * w2.x + mi.w * w3.x + bb.x;
    o.y = mi.x * w0.y + mi.y * w1.y + mi.z * w2.y + mi.w * w3.y + bb.y;
    o.z = mi.x * w0.z + mi.y * w1.z + mi.z * w2.z + mi.w * w3.z + bb.z;
    o.w = mi.x * w0.w + mi.y * w1.w + mi.z * w2.w + mi.w * w3.w + bb.w;
    ((float4*)out)[t] = o;
}

extern "C" void kernel_launch(void* const* d_in, const int* in_sizes, int n_in,
                              void* d_out, int out_size, void* d_ws, size_t ws_size,
                              hipStream_t stream) {
    const float* x  = (const float*)d_in[0];
    const int*   ei = (const int*)d_in[1];     // int64 in ref -> pushed as int32
    const float* W  = (const float*)d_in[2];
    const float* b  = (const float*)d_in[3];
    float* out = (float*)d_out;

    int n = in_sizes[0] / 4;       // 100000
    int E = in_sizes[1] / 2;       // 640000
    const int* row = ei;           // sources
    const int* col = ei + E;       // targets

    int nbk = (n + PSB - 1) >> LGP;            // 98 buckets

    // ws layout (4B words):
    //  sx[4n] | dis[n] | m[4n] | brow[E] | blc[(E+1)/2] | bcntT[NBKM*NB]
    //  | cpart[NBKM*NB] | btot[NBKM] | boffs[NBKM] | degrep[GB2*NSTR] | repB[GB2*NSTR*4]
    size_t o_sx    = 0;
    size_t o_dis   = o_sx + 4 * (size_t)n;
    size_t o_m     = o_dis + (size_t)n;
    size_t o_brow  = o_m + 4 * (size_t)n;
    size_t o_blc   = o_brow + (size_t)E;
    size_t o_bcnt  = o_blc + ((size_t)E + 1) / 2;
    size_t o_cpart = o_bcnt + (size_t)NBKM * NB;
    size_t o_btot  = o_cpart + (size_t)NBKM * NB;
    size_t o_boffs = o_btot + NBKM;
    size_t o_deg   = o_boffs + NBKM;
    size_t o_repB  = (o_deg + (size_t)GB2 * NSTR + 3) & ~(size_t)3;

    float*          sx    = (float*)d_ws + o_sx;
    float*          dis   = (float*)d_ws + o_dis;
    float*          mbuf  = (float*)d_ws + o_m;
    int*            brow  = (int*)d_ws + o_brow;
    unsigned short* blc   = (unsigned short*)((float*)d_ws + o_blc);
    unsigned int*   bcntT = (unsigned int*)d_ws + o_bcnt;
    unsigned int*   cpart = (unsigned int*)d_ws + o_cpart;
    unsigned int*   btot  = (unsigned int*)d_ws + o_btot;
    unsigned int*   boffs = (unsigned int*)d_ws + o_boffs;
    unsigned int*   degrep= (unsigned int*)d_ws + o_deg;
    float4*         repB  = (float4*)((float*)d_ws + o_repB);

    k_bcnt   <<<NB, BLK, 0, stream>>>(col, E, nbk, bcntT);
    k_scan1  <<<nbk, NB, 0, stream>>>(bcntT, cpart, btot);
    k_scan2  <<<1, NBKM, 0, stream>>>(btot, boffs, nbk);
    k_bfill  <<<NB, BLK, 0, stream>>>(row, col, cpart, boffs, blc, brow, E, nbk);
    k_bdeg   <<<nbk * GB2, BLK, 0, stream>>>(blc, boffs, btot, degrep);
    k_dsx    <<<(n + BLK - 1) / BLK, BLK, 0, stream>>>(degrep, (const float4*)x,
                                                       (float4*)sx, dis, n);
    k_baggB  <<<nbk * GB2, BLK, 0, stream>>>(blc, brow, (const float4*)sx,
                                             boffs, btot, repB);
    k_reduceB<<<(n + BLK - 1) / BLK, BLK, 0, stream>>>(repB, (const float4*)sx, dis,
                                                       (float4*)mbuf, n);
    int oT = n * 32;
    k_out    <<<(oT + BLK - 1) / BLK, BLK, 0, stream>>>((const float4*)mbuf, W, b, out, n);
}